// Round 1
// baseline (384.777 us; speedup 1.0000x reference)
//
#include <hip/hip_runtime.h>
#include <math.h>

#define B 8
#define D 512
#define N 1600
#define NRES 40

static constexpr float EPS_K   = 1e-6f;
static constexpr float INV_T   = 10.0f;  // 1/T
static constexpr float SCALE_K = 10.0f;

// ws layout (4-byte units):
// [0, 12800)      norm1[b][n]
// [12800, 25600)  norm2[b][n]
// [25600, 38400)  mx[b][n]    (uint bits of float max over m)
// [38400, 51200)  bestm[b][n] (int argmax)

// ---------------- Kernel 1: column norms ----------------
__global__ __launch_bounds__(256)
void norms_kernel(const float* __restrict__ fs1, const float* __restrict__ fs2,
                  float* __restrict__ norm1, float* __restrict__ norm2) {
    int bid   = blockIdx.x;          // 0 .. 2*B*25-1
    int ntile = bid % 25;
    int b     = (bid / 25) % B;
    int which = bid / (25 * B);
    const float* src = which ? fs2 : fs1;
    float*       dst = which ? norm2 : norm1;

    int t    = threadIdx.x;
    int nl   = t & 63;
    int doff = t >> 6;               // 0..3
    int n    = ntile * 64 + nl;
    const float* base = src + (size_t)b * D * N + n;

    float acc = 0.f;
    for (int d = doff; d < D; d += 4) {
        float v = base[(size_t)d * N];
        acc = fmaf(v, v, acc);
    }
    __shared__ float red[4][64];
    red[doff][nl] = acc;
    __syncthreads();
    if (t < 64) {
        float s = red[0][t] + red[1][t] + red[2][t] + red[3][t];
        dst[b * N + ntile * 64 + t] = sqrtf(s);
    }
}

// ---------------- Kernel 2: GEMM + exp + per-n max ----------------
#define BK 16
#define BT 128

__global__ __launch_bounds__(256)
void gemm_exp_kernel(const float* __restrict__ fs1, const float* __restrict__ fs2,
                     const float* __restrict__ norm1, const float* __restrict__ norm2,
                     unsigned int* __restrict__ mx, float* __restrict__ out) {
    int m0 = blockIdx.x * BT;
    int n0 = blockIdx.y * BT;
    int b  = blockIdx.z;
    int t  = threadIdx.x;
    int tx = t & 15;     // m group
    int ty = t >> 4;     // n group

    __shared__ float Xs[BK][BT];
    __shared__ float Ys[BK][BT];
    __shared__ float red[BT][17];

    const float* Xb = fs1 + (size_t)b * D * N;
    const float* Yb = fs2 + (size_t)b * D * N;

    float acc[8][8];
    #pragma unroll
    for (int i = 0; i < 8; i++)
        #pragma unroll
        for (int j = 0; j < 8; j++) acc[i][j] = 0.f;

    int  r0  = t >> 5;          // 0..7
    int  c4  = (t & 31) * 4;    // 0..124
    bool xok = (n0 + c4) < N;   // float4 is fully valid or fully OOB (all offsets %4==0)
    bool yok = (m0 + c4) < N;

    for (int kk = 0; kk < D; kk += BK) {
        #pragma unroll
        for (int rr = 0; rr < 2; rr++) {
            int r = r0 + rr * 8;
            int d = kk + r;
            float4 xv = make_float4(0.f, 0.f, 0.f, 0.f);
            float4 yv = make_float4(0.f, 0.f, 0.f, 0.f);
            if (xok) xv = *(const float4*)&Xb[(size_t)d * N + n0 + c4];
            if (yok) yv = *(const float4*)&Yb[(size_t)d * N + m0 + c4];
            *(float4*)&Xs[r][c4] = xv;
            *(float4*)&Ys[r][c4] = yv;
        }
        __syncthreads();
        #pragma unroll
        for (int d = 0; d < BK; d++) {
            float4 a0 = *(const float4*)&Xs[d][ty * 4];
            float4 a1 = *(const float4*)&Xs[d][64 + ty * 4];
            float4 b0 = *(const float4*)&Ys[d][tx * 4];
            float4 b1 = *(const float4*)&Ys[d][64 + tx * 4];
            float av[8] = {a0.x, a0.y, a0.z, a0.w, a1.x, a1.y, a1.z, a1.w};
            float bv[8] = {b0.x, b0.y, b0.z, b0.w, b1.x, b1.y, b1.z, b1.w};
            #pragma unroll
            for (int i = 0; i < 8; i++)
                #pragma unroll
                for (int j = 0; j < 8; j++)
                    acc[i][j] = fmaf(av[i], bv[j], acc[i][j]);
        }
        __syncthreads();
    }

    // epilogue
    int   ng[8], mg[8];
    float n1v[8], n2v[8];
    #pragma unroll
    for (int q = 0; q < 8; q++) {
        ng[q] = n0 + ((q < 4) ? (ty * 4 + q) : (64 + ty * 4 + q - 4));
        mg[q] = m0 + ((q < 4) ? (tx * 4 + q) : (64 + tx * 4 + q - 4));
        n1v[q] = (ng[q] < N) ? norm1[b * N + ng[q]] : 1.f;
        n2v[q] = (mg[q] < N) ? norm2[b * N + mg[q]] : 1.f;
    }
    float pmax[8];
    #pragma unroll
    for (int i = 0; i < 8; i++) pmax[i] = 0.f;

    size_t obase = (size_t)b * N * N;
    #pragma unroll
    for (int j = 0; j < 8; j++) {
        float kcol[8];
        #pragma unroll
        for (int i = 0; i < 8; i++) {
            float c = acc[i][j] / (n1v[i] * n2v[j] + EPS_K);
            float k = expf((c - 1.f) * INV_T);
            if (mg[j] >= N) k = 0.f;   // excluded from max, never stored
            kcol[i] = k;
            pmax[i] = fmaxf(pmax[i], k);
        }
        if (mg[j] < N) {
            size_t rowb = obase + (size_t)mg[j] * N;
            float4 v0 = {kcol[0], kcol[1], kcol[2], kcol[3]};
            *(float4*)&out[rowb + ng[0]] = v0;           // ng[0..3] always < N
            if (ng[4] < N) {
                float4 v1 = {kcol[4], kcol[5], kcol[6], kcol[7]};
                *(float4*)&out[rowb + ng[4]] = v1;
            }
        }
    }

    // per-n block max -> atomicMax (uint bits; all K > 0)
    #pragma unroll
    for (int q = 0; q < 8; q++) {
        int nloc = (q < 4) ? (ty * 4 + q) : (64 + ty * 4 + q - 4);
        red[nloc][tx] = pmax[q];
    }
    __syncthreads();
    if (t < BT) {
        float mval = red[t][0];
        #pragma unroll
        for (int x = 1; x < 16; x++) mval = fmaxf(mval, red[t][x]);
        int n = n0 + t;
        if (n < N) atomicMax(&mx[b * N + n], __float_as_uint(mval));
    }
}

// ---------------- Kernel 3: in-place fixup + argmax ----------------
__global__ __launch_bounds__(256)
void fix_argmax_kernel(float* __restrict__ out, const unsigned int* __restrict__ mx,
                       int* __restrict__ bestm) {
    int ntile = blockIdx.x;   // 25
    int mq    = blockIdx.y;   // 4
    int b     = blockIdx.z;   // 8
    int t     = threadIdx.x;
    int nl    = t & 63;
    int moff  = t >> 6;       // 0..3
    int n     = ntile * 64 + nl;

    float  mxv  = __uint_as_float(mx[b * N + n]);
    int    best = 0x7fffffff;
    size_t base = (size_t)b * N * N + n;
    int mend = mq * 400 + 400;
    for (int m = mq * 400 + moff; m < mend; m += 4) {
        size_t idx = base + (size_t)m * N;
        float  v   = out[idx];
        out[idx]   = (v - mxv) * SCALE_K;
        if (v == mxv) best = min(best, m);
    }
    __shared__ int red[4][64];
    red[moff][nl] = best;
    __syncthreads();
    if (moff == 0) {
        int bm = min(min(red[0][nl], red[1][nl]), min(red[2][nl], red[3][nl]));
        if (bm < 0x7fffffff) atomicMin(&bestm[b * N + n], bm);
    }
}

// ---------------- Kernel 4: flow + certainty ----------------
__global__ __launch_bounds__(256)
void flow_kernel(float* __restrict__ out, const int* __restrict__ bestm) {
    int id = blockIdx.x * 256 + threadIdx.x;
    if (id >= B * N) return;
    int b = id / N, n = id % N;
    int bm = bestm[id];
    int i = bm / NRES, j = bm % NRES;
    const float step = 1.95f / 39.f;  // 0.05
    float gx = fmaf(step, (float)j, -0.975f);
    float gy = fmaf(step, (float)i, -0.975f);
    const size_t CERT_OFF = (size_t)B * N * N;
    const size_t FLOW_OFF = CERT_OFF + (size_t)B * N;
    out[CERT_OFF + id] = 0.f;
    out[FLOW_OFF + (size_t)(b * 2) * N + n]     = gx;
    out[FLOW_OFF + (size_t)(b * 2 + 1) * N + n] = gy;
}

extern "C" void kernel_launch(void* const* d_in, const int* in_sizes, int n_in,
                              void* d_out, int out_size, void* d_ws, size_t ws_size,
                              hipStream_t stream) {
    const float* fs1 = (const float*)d_in[0];
    const float* fs2 = (const float*)d_in[1];
    float* out = (float*)d_out;

    float*        norm1 = (float*)d_ws;
    float*        norm2 = norm1 + B * N;
    unsigned int* mx    = (unsigned int*)(norm2 + B * N);
    int*          bestm = (int*)(mx + B * N);

    hipMemsetAsync(mx, 0, B * N * sizeof(unsigned int), stream);
    hipMemsetAsync(bestm, 0x7f, B * N * sizeof(int), stream);

    norms_kernel<<<dim3(2 * B * 25), 256, 0, stream>>>(fs1, fs2, norm1, norm2);
    gemm_exp_kernel<<<dim3(13, 13, B), 256, 0, stream>>>(fs1, fs2, norm1, norm2, mx, out);
    fix_argmax_kernel<<<dim3(25, 4, B), 256, 0, stream>>>(out, mx, bestm);
    flow_kernel<<<dim3((B * N + 255) / 256), 256, 0, stream>>>(out, bestm);
}

// Round 2
// 304.092 us; speedup vs baseline: 1.2653x; 1.2653x over previous
//
#include <hip/hip_runtime.h>
#include <math.h>

#define B 8
#define D 512
#define N 1600
#define NP 1664      // padded N (13 * 128)
#define NRES 40

static constexpr float EPS_K   = 1e-6f;
static constexpr float INV_T   = 10.0f;  // 1/T
static constexpr float SCALE_K = 10.0f;

using f32x4 = __attribute__((ext_vector_type(4))) float;
using s8    = __attribute__((ext_vector_type(8))) short;

// ---------------- helpers ----------------
__device__ __forceinline__ unsigned short b16rn(float v) {
    unsigned int u = __float_as_uint(v);
    return (unsigned short)((u + 0x7fffu + ((u >> 16) & 1u)) >> 16);
}
__device__ __forceinline__ float b2f(unsigned short s) {
    return __uint_as_float(((unsigned int)s) << 16);
}
__device__ __forceinline__ void gload16(const void* g, void* l) {
    __builtin_amdgcn_global_load_lds(
        (const __attribute__((address_space(1))) void*)g,
        (__attribute__((address_space(3))) void*)l, 16, 0, 0);
}

// ---------------- Kernel A: split fp32 -> 3x bf16, transposed to [b][n][d] ----------------
__global__ __launch_bounds__(256)
void split_transpose_kernel(const float* __restrict__ f1, const float* __restrict__ f2,
                            short* __restrict__ Xh, short* __restrict__ Xm, short* __restrict__ Xl,
                            short* __restrict__ Yh, short* __restrict__ Ym, short* __restrict__ Yl) {
    int bx = blockIdx.x;           // n-tile of 64 (0..25, covers NP)
    int by = blockIdx.y;           // d-tile of 64 (0..7)
    int bz = blockIdx.z;
    int b = bz & 7, which = bz >> 3;
    const float* src = which ? f2 : f1;
    short* oh = which ? Yh : Xh;
    short* om = which ? Ym : Xm;
    short* ol = which ? Yl : Xl;

    __shared__ float Ts[64][65];
    int t = threadIdx.x;
    int n0 = bx * 64, d0 = by * 64;
    bool valid = (n0 < N);         // bx==25 is the zero-pad tile
    int c4 = (t & 15) * 4, g16 = t >> 4;

    #pragma unroll
    for (int p = 0; p < 4; ++p) {
        int dl = g16 + p * 16;
        float4 v = make_float4(0.f, 0.f, 0.f, 0.f);
        if (valid) v = *(const float4*)&src[((size_t)b * D + d0 + dl) * N + n0 + c4];
        Ts[dl][c4 + 0] = v.x; Ts[dl][c4 + 1] = v.y;
        Ts[dl][c4 + 2] = v.z; Ts[dl][c4 + 3] = v.w;
    }
    __syncthreads();
    #pragma unroll
    for (int p = 0; p < 4; ++p) {
        int nl = g16 + p * 16;
        unsigned int hh[2], mm_[2], ll[2];
        #pragma unroll
        for (int q = 0; q < 2; ++q) {
            unsigned int hw = 0, mw = 0, lw = 0;
            #pragma unroll
            for (int i = 0; i < 2; ++i) {
                float v = Ts[c4 + q * 2 + i][nl];
                unsigned short h = b16rn(v);
                float r1 = v - b2f(h);
                unsigned short m_ = b16rn(r1);
                float r2 = r1 - b2f(m_);
                unsigned short lo = b16rn(r2);
                hw |= ((unsigned int)h) << (16 * i);
                mw |= ((unsigned int)m_) << (16 * i);
                lw |= ((unsigned int)lo) << (16 * i);
            }
            hh[q] = hw; mm_[q] = mw; ll[q] = lw;
        }
        size_t o = ((size_t)b * NP + n0 + nl) * D + d0 + c4;
        *(uint2*)&oh[o] = make_uint2(hh[0], hh[1]);
        *(uint2*)&om[o] = make_uint2(mm_[0], mm_[1]);
        *(uint2*)&ol[o] = make_uint2(ll[0], ll[1]);
    }
}

// ---------------- Kernel B: column norms (fp32, deterministic) ----------------
__global__ __launch_bounds__(256)
void norms_kernel(const float* __restrict__ fs1, const float* __restrict__ fs2,
                  float* __restrict__ norm1, float* __restrict__ norm2) {
    int bid   = blockIdx.x;
    int ntile = bid % 25;
    int b     = (bid / 25) % B;
    int which = bid / (25 * B);
    const float* src = which ? fs2 : fs1;
    float*       dst = which ? norm2 : norm1;

    int t = threadIdx.x, nl = t & 63, doff = t >> 6;
    int n = ntile * 64 + nl;
    const float* base = src + (size_t)b * D * N + n;
    float acc = 0.f;
    for (int d = doff; d < D; d += 4) {
        float v = base[(size_t)d * N];
        acc = fmaf(v, v, acc);
    }
    __shared__ float red[4][64];
    red[doff][nl] = acc;
    __syncthreads();
    if (t < 64) {
        float s = red[0][t] + red[1][t] + red[2][t] + red[3][t];
        dst[b * N + ntile * 64 + t] = sqrtf(s);
    }
}

// ---------------- Kernel C: bf16x3 MFMA GEMM + exp + per-n max ----------------
__device__ __forceinline__ s8 ldfrag(const short* tile, int row, int l) {
    int s = ((l >> 4) ^ (row >> 1)) & 3;   // bank-spread XOR swizzle
    return *(const s8*)(tile + row * 32 + s * 8);
}

__global__ __launch_bounds__(256, 3)
void gemm_mfma_kernel(const short* __restrict__ Yh, const short* __restrict__ Ym, const short* __restrict__ Yl,
                      const short* __restrict__ Xh, const short* __restrict__ Xm, const short* __restrict__ Xl,
                      const float* __restrict__ norm1, const float* __restrict__ norm2,
                      unsigned int* __restrict__ mx, float* __restrict__ out) {
    int m0 = blockIdx.x * 128;     // rows of output (target index m, from fs_2)
    int n0 = blockIdx.y * 128;     // cols of output (source index n, from fs_1)
    int b  = blockIdx.z;
    int t  = threadIdx.x;
    int l  = t & 63;
    int wid = t >> 6;
    int mwoff = (wid & 1) * 64;
    int nwoff = (wid >> 1) * 64;

    __shared__ short sYh[128 * 32], sYm[128 * 32], sYl[128 * 32];
    __shared__ short sXh[128 * 32], sXm[128 * 32], sXl[128 * 32];

    f32x4 acc[4][4];
    #pragma unroll
    for (int i = 0; i < 4; i++)
        #pragma unroll
        for (int j = 0; j < 4; j++) acc[i][j] = (f32x4)0.f;

    size_t bNP = (size_t)b * NP;
    int lr = l >> 2;          // 0..15: row within 16-row chunk
    int ls = l & 3;           // 0..3 : 16B slot within 64B row

    for (int kk = 0; kk < D; kk += 32) {
        // stage 6 tiles of [128 rows][32 k] bf16; pre-swizzled global source:
        // LDS linear slot gets content of global slot ^ ((row>>1)&3)
        #define STAGE(LDST, GBASE, ROW0)                                              \
        {                                                                             \
            _Pragma("unroll")                                                         \
            for (int jj = 0; jj < 2; ++jj) {                                          \
                int rgrp = wid + jj * 4;                                              \
                int row  = rgrp * 16 + lr;                                            \
                int slot = (ls ^ (row >> 1)) & 3;                                     \
                const short* src = GBASE + (bNP + ROW0 + row) * D + kk + slot * 8;    \
                gload16(src, LDST + rgrp * 512);                                      \
            }                                                                         \
        }
        STAGE(sYh, Yh, m0) STAGE(sYm, Ym, m0) STAGE(sYl, Yl, m0)
        STAGE(sXh, Xh, n0) STAGE(sXm, Xm, n0) STAGE(sXl, Xl, n0)
        #undef STAGE
        __syncthreads();

        s8 bh[4], bm[4], bl[4];
        #pragma unroll
        for (int nj = 0; nj < 4; ++nj) {
            int nrow = nwoff + nj * 16 + (l & 15);
            bh[nj] = ldfrag(sXh, nrow, l);
            bm[nj] = ldfrag(sXm, nrow, l);
            bl[nj] = ldfrag(sXl, nrow, l);
        }
        #pragma unroll
        for (int mi = 0; mi < 4; ++mi) {
            int mrow = mwoff + mi * 16 + (l & 15);
            s8 ah = ldfrag(sYh, mrow, l);
            s8 am = ldfrag(sYm, mrow, l);
            s8 al = ldfrag(sYl, mrow, l);
            #pragma unroll
            for (int nj = 0; nj < 4; ++nj) {
                f32x4 c = acc[mi][nj];
                c = __builtin_amdgcn_mfma_f32_16x16x32_bf16(ah, bh[nj], c, 0, 0, 0);
                c = __builtin_amdgcn_mfma_f32_16x16x32_bf16(ah, bm[nj], c, 0, 0, 0);
                c = __builtin_amdgcn_mfma_f32_16x16x32_bf16(am, bh[nj], c, 0, 0, 0);
                c = __builtin_amdgcn_mfma_f32_16x16x32_bf16(am, bm[nj], c, 0, 0, 0);
                c = __builtin_amdgcn_mfma_f32_16x16x32_bf16(ah, bl[nj], c, 0, 0, 0);
                c = __builtin_amdgcn_mfma_f32_16x16x32_bf16(al, bh[nj], c, 0, 0, 0);
                acc[mi][nj] = c;
            }
        }
        __syncthreads();
    }

    // epilogue: cos -> K = exp((c-1)*10); store out[b][m][n]; per-n max
    int hi4 = l >> 4;
    float n1v[4];
    int   ng[4];
    #pragma unroll
    for (int nj = 0; nj < 4; ++nj) {
        ng[nj]  = n0 + nwoff + nj * 16 + (l & 15);
        n1v[nj] = (ng[nj] < N) ? norm1[b * N + ng[nj]] : 1.f;
    }
    float pmax[4] = {0.f, 0.f, 0.f, 0.f};
    size_t obase = (size_t)b * N * N;

    #pragma unroll
    for (int mi = 0; mi < 4; ++mi) {
        #pragma unroll
        for (int r = 0; r < 4; ++r) {
            int mg = m0 + mwoff + mi * 16 + hi4 * 4 + r;
            bool mok = (mg < N);
            float n2v = mok ? norm2[b * N + mg] : 1.f;
            #pragma unroll
            for (int nj = 0; nj < 4; ++nj) {
                float c = acc[mi][nj][r] / (n2v * n1v[nj] + EPS_K);
                float k = expf((c - 1.f) * INV_T);
                if (!mok) k = 0.f;
                pmax[nj] = fmaxf(pmax[nj], k);
                if (mok && ng[nj] < N)
                    out[obase + (size_t)mg * N + ng[nj]] = k;
            }
        }
    }
    #pragma unroll
    for (int nj = 0; nj < 4; ++nj) {
        float v = pmax[nj];
        v = fmaxf(v, __shfl_xor(v, 16, 64));
        v = fmaxf(v, __shfl_xor(v, 32, 64));
        if (hi4 == 0 && ng[nj] < N)
            atomicMax(&mx[b * N + ng[nj]], __float_as_uint(v));
    }
}

// ---------------- fp32 fallback GEMM (used if ws too small) ----------------
#define BK 16
#define BT 128
__global__ __launch_bounds__(256)
void gemm_exp_kernel(const float* __restrict__ fs1, const float* __restrict__ fs2,
                     const float* __restrict__ norm1, const float* __restrict__ norm2,
                     unsigned int* __restrict__ mx, float* __restrict__ out) {
    int m0 = blockIdx.x * BT, n0 = blockIdx.y * BT, b = blockIdx.z;
    int t = threadIdx.x, tx = t & 15, ty = t >> 4;
    __shared__ float Xs[BK][BT];
    __shared__ float Ys[BK][BT];
    __shared__ float red[BT][17];
    const float* Xb = fs1 + (size_t)b * D * N;
    const float* Yb = fs2 + (size_t)b * D * N;
    float acc[8][8];
    #pragma unroll
    for (int i = 0; i < 8; i++)
        #pragma unroll
        for (int j = 0; j < 8; j++) acc[i][j] = 0.f;
    int r0 = t >> 5, c4 = (t & 31) * 4;
    bool xok = (n0 + c4) < N, yok = (m0 + c4) < N;
    for (int kk = 0; kk < D; kk += BK) {
        #pragma unroll
        for (int rr = 0; rr < 2; rr++) {
            int r = r0 + rr * 8, d = kk + r;
            float4 xv = make_float4(0, 0, 0, 0), yv = make_float4(0, 0, 0, 0);
            if (xok) xv = *(const float4*)&Xb[(size_t)d * N + n0 + c4];
            if (yok) yv = *(const float4*)&Yb[(size_t)d * N + m0 + c4];
            *(float4*)&Xs[r][c4] = xv;
            *(float4*)&Ys[r][c4] = yv;
        }
        __syncthreads();
        #pragma unroll
        for (int d = 0; d < BK; d++) {
            float4 a0 = *(const float4*)&Xs[d][ty * 4];
            float4 a1 = *(const float4*)&Xs[d][64 + ty * 4];
            float4 b0 = *(const float4*)&Ys[d][tx * 4];
            float4 b1 = *(const float4*)&Ys[d][64 + tx * 4];
            float av[8] = {a0.x, a0.y, a0.z, a0.w, a1.x, a1.y, a1.z, a1.w};
            float bv[8] = {b0.x, b0.y, b0.z, b0.w, b1.x, b1.y, b1.z, b1.w};
            #pragma unroll
            for (int i = 0; i < 8; i++)
                #pragma unroll
                for (int j = 0; j < 8; j++)
                    acc[i][j] = fmaf(av[i], bv[j], acc[i][j]);
        }
        __syncthreads();
    }
    int ng[8], mg[8];
    float n1v[8], n2v[8];
    #pragma unroll
    for (int q = 0; q < 8; q++) {
        ng[q] = n0 + ((q < 4) ? (ty * 4 + q) : (64 + ty * 4 + q - 4));
        mg[q] = m0 + ((q < 4) ? (tx * 4 + q) : (64 + tx * 4 + q - 4));
        n1v[q] = (ng[q] < N) ? norm1[b * N + ng[q]] : 1.f;
        n2v[q] = (mg[q] < N) ? norm2[b * N + mg[q]] : 1.f;
    }
    float pmax[8];
    #pragma unroll
    for (int i = 0; i < 8; i++) pmax[i] = 0.f;
    size_t obase = (size_t)b * N * N;
    #pragma unroll
    for (int j = 0; j < 8; j++) {
        float kcol[8];
        #pragma unroll
        for (int i = 0; i < 8; i++) {
            float c = acc[i][j] / (n1v[i] * n2v[j] + EPS_K);
            float k = expf((c - 1.f) * INV_T);
            if (mg[j] >= N) k = 0.f;
            kcol[i] = k;
            pmax[i] = fmaxf(pmax[i], k);
        }
        if (mg[j] < N) {
            size_t rowb = obase + (size_t)mg[j] * N;
            float4 v0 = {kcol[0], kcol[1], kcol[2], kcol[3]};
            *(float4*)&out[rowb + ng[0]] = v0;
            if (ng[4] < N) {
                float4 v1 = {kcol[4], kcol[5], kcol[6], kcol[7]};
                *(float4*)&out[rowb + ng[4]] = v1;
            }
        }
    }
    #pragma unroll
    for (int q = 0; q < 8; q++) {
        int nloc = (q < 4) ? (ty * 4 + q) : (64 + ty * 4 + q - 4);
        red[nloc][tx] = pmax[q];
    }
    __syncthreads();
    if (t < BT) {
        float mval = red[t][0];
        #pragma unroll
        for (int x = 1; x < 16; x++) mval = fmaxf(mval, red[t][x]);
        int n = n0 + t;
        if (n < N) atomicMax(&mx[b * N + n], __float_as_uint(mval));
    }
}

// ---------------- Kernel D: in-place fixup + argmax ----------------
__global__ __launch_bounds__(256)
void fix_argmax_kernel(float* __restrict__ out, const unsigned int* __restrict__ mx,
                       int* __restrict__ bestm) {
    int ntile = blockIdx.x, mq = blockIdx.y, b = blockIdx.z;
    int t = threadIdx.x, nl = t & 63, moff = t >> 6;
    int n = ntile * 64 + nl;
    float mxv = __uint_as_float(mx[b * N + n]);
    int best = 0x7fffffff;
    size_t base = (size_t)b * N * N + n;
    int mend = mq * 400 + 400;
    for (int m = mq * 400 + moff; m < mend; m += 4) {
        size_t idx = base + (size_t)m * N;
        float v = out[idx];
        out[idx] = (v - mxv) * SCALE_K;
        if (v == mxv) best = min(best, m);
    }
    __shared__ int red[4][64];
    red[moff][nl] = best;
    __syncthreads();
    if (moff == 0) {
        int bm = min(min(red[0][nl], red[1][nl]), min(red[2][nl], red[3][nl]));
        if (bm < 0x7fffffff) atomicMin(&bestm[b * N + n], bm);
    }
}

// ---------------- Kernel E: flow + certainty ----------------
__global__ __launch_bounds__(256)
void flow_kernel(float* __restrict__ out, const int* __restrict__ bestm) {
    int id = blockIdx.x * 256 + threadIdx.x;
    if (id >= B * N) return;
    int b = id / N, n = id % N;
    int bm = bestm[id];
    int i = bm / NRES, j = bm % NRES;
    const float step = 1.95f / 39.f;
    float gx = fmaf(step, (float)j, -0.975f);
    float gy = fmaf(step, (float)i, -0.975f);
    const size_t CERT_OFF = (size_t)B * N * N;
    const size_t FLOW_OFF = CERT_OFF + (size_t)B * N;
    out[CERT_OFF + id] = 0.f;
    out[FLOW_OFF + (size_t)(b * 2) * N + n]     = gx;
    out[FLOW_OFF + (size_t)(b * 2 + 1) * N + n] = gy;
}

extern "C" void kernel_launch(void* const* d_in, const int* in_sizes, int n_in,
                              void* d_out, int out_size, void* d_ws, size_t ws_size,
                              hipStream_t stream) {
    const float* fs1 = (const float*)d_in[0];
    const float* fs2 = (const float*)d_in[1];
    float* out = (float*)d_out;

    const size_t SPLIT = (size_t)B * NP * D;                 // elems per split
    const size_t NEED  = 6 * SPLIT * sizeof(short) + 4 * (size_t)B * N * 4 + 64;

    if (ws_size >= NEED) {
        short* Yh = (short*)d_ws;
        short* Ym = Yh + SPLIT;
        short* Yl = Ym + SPLIT;
        short* Xh = Yl + SPLIT;
        short* Xm = Xh + SPLIT;
        short* Xl = Xm + SPLIT;
        float* norm1 = (float*)(Xl + SPLIT);
        float* norm2 = norm1 + B * N;
        unsigned int* mx = (unsigned int*)(norm2 + B * N);
        int* bestm = (int*)(mx + B * N);

        hipMemsetAsync(mx, 0, B * N * sizeof(unsigned int), stream);
        hipMemsetAsync(bestm, 0x7f, B * N * sizeof(int), stream);

        split_transpose_kernel<<<dim3(26, 8, 16), 256, 0, stream>>>(fs1, fs2, Xh, Xm, Xl, Yh, Ym, Yl);
        norms_kernel<<<dim3(2 * B * 25), 256, 0, stream>>>(fs1, fs2, norm1, norm2);
        gemm_mfma_kernel<<<dim3(13, 13, B), 256, 0, stream>>>(Yh, Ym, Yl, Xh, Xm, Xl,
                                                              norm1, norm2, mx, out);
        fix_argmax_kernel<<<dim3(25, 4, B), 256, 0, stream>>>(out, mx, bestm);
        flow_kernel<<<dim3((B * N + 255) / 256), 256, 0, stream>>>(out, bestm);
    } else {
        float* norm1 = (float*)d_ws;
        float* norm2 = norm1 + B * N;
        unsigned int* mx = (unsigned int*)(norm2 + B * N);
        int* bestm = (int*)(mx + B * N);

        hipMemsetAsync(mx, 0, B * N * sizeof(unsigned int), stream);
        hipMemsetAsync(bestm, 0x7f, B * N * sizeof(int), stream);

        norms_kernel<<<dim3(2 * B * 25), 256, 0, stream>>>(fs1, fs2, norm1, norm2);
        gemm_exp_kernel<<<dim3(13, 13, B), 256, 0, stream>>>(fs1, fs2, norm1, norm2, mx, out);
        fix_argmax_kernel<<<dim3(25, 4, B), 256, 0, stream>>>(out, mx, bestm);
        flow_kernel<<<dim3((B * N + 255) / 256), 256, 0, stream>>>(out, bestm);
    }
}

// Round 3
// 227.843 us; speedup vs baseline: 1.6888x; 1.3347x over previous
//
#include <hip/hip_runtime.h>
#include <math.h>

#define B 8
#define D 512
#define N 1600
#define NP 1664      // padded N (13 * 128)
#define NRES 40

static constexpr float EPS_K   = 1e-6f;
static constexpr float INV_T   = 10.0f;  // 1/T
static constexpr float SCALE_K = 10.0f;

using f32x4 = __attribute__((ext_vector_type(4))) float;
using s8    = __attribute__((ext_vector_type(8))) short;

// ---------------- helpers ----------------
__device__ __forceinline__ unsigned short b16rn(float v) {
    unsigned int u = __float_as_uint(v);
    return (unsigned short)((u + 0x7fffu + ((u >> 16) & 1u)) >> 16);
}
__device__ __forceinline__ float b2f(unsigned short s) {
    return __uint_as_float(((unsigned int)s) << 16);
}
__device__ __forceinline__ void gload16(const void* g, void* l) {
    __builtin_amdgcn_global_load_lds(
        (const __attribute__((address_space(1))) void*)g,
        (__attribute__((address_space(3))) void*)l, 16, 0, 0);
}

// ---------------- Kernel A: split fp32 -> 3x bf16 transposed + norm partials ----------------
// partial layout in scratch (d_out head, overwritten later by gemm):
//   partial[((which*8 + b)*8 + dtile)*NP + n]
__global__ __launch_bounds__(256)
void split_transpose_kernel(const float* __restrict__ f1, const float* __restrict__ f2,
                            short* __restrict__ Xh, short* __restrict__ Xm, short* __restrict__ Xl,
                            short* __restrict__ Yh, short* __restrict__ Ym, short* __restrict__ Yl,
                            float* __restrict__ partial) {
    int bx = blockIdx.x;           // n-tile of 64 (0..25, covers NP)
    int by = blockIdx.y;           // d-tile of 64 (0..7)
    int bz = blockIdx.z;
    int b = bz & 7, which = bz >> 3;
    const float* src = which ? f2 : f1;
    short* oh = which ? Yh : Xh;
    short* om = which ? Ym : Xm;
    short* ol = which ? Yl : Xl;

    __shared__ float Ts[64][65];
    __shared__ float red[64][17];
    int t = threadIdx.x;
    int n0 = bx * 64, d0 = by * 64;
    bool valid = (n0 < N);         // bx==25 is the zero-pad tile
    int c4 = (t & 15) * 4, g16 = t >> 4;

    #pragma unroll
    for (int p = 0; p < 4; ++p) {
        int dl = g16 + p * 16;
        float4 v = make_float4(0.f, 0.f, 0.f, 0.f);
        if (valid) v = *(const float4*)&src[((size_t)b * D + d0 + dl) * N + n0 + c4];
        Ts[dl][c4 + 0] = v.x; Ts[dl][c4 + 1] = v.y;
        Ts[dl][c4 + 2] = v.z; Ts[dl][c4 + 3] = v.w;
    }
    __syncthreads();
    #pragma unroll
    for (int p = 0; p < 4; ++p) {
        int nl = g16 + p * 16;
        unsigned int hh[2], mm_[2], ll[2];
        float ssp = 0.f;
        #pragma unroll
        for (int q = 0; q < 2; ++q) {
            unsigned int hw = 0, mw = 0, lw = 0;
            #pragma unroll
            for (int i = 0; i < 2; ++i) {
                float v = Ts[c4 + q * 2 + i][nl];
                ssp = fmaf(v, v, ssp);
                unsigned short h = b16rn(v);
                float r1 = v - b2f(h);
                unsigned short m_ = b16rn(r1);
                float r2 = r1 - b2f(m_);
                unsigned short lo = b16rn(r2);
                hw |= ((unsigned int)h) << (16 * i);
                mw |= ((unsigned int)m_) << (16 * i);
                lw |= ((unsigned int)lo) << (16 * i);
            }
            hh[q] = hw; mm_[q] = mw; ll[q] = lw;
        }
        red[nl][c4 >> 2] = ssp;
        size_t o = ((size_t)b * NP + n0 + nl) * D + d0 + c4;
        *(uint2*)&oh[o] = make_uint2(hh[0], hh[1]);
        *(uint2*)&om[o] = make_uint2(mm_[0], mm_[1]);
        *(uint2*)&ol[o] = make_uint2(ll[0], ll[1]);
    }
    __syncthreads();
    if (t < 64) {
        float s = 0.f;
        #pragma unroll
        for (int g = 0; g < 16; ++g) s += red[t][g];
        partial[(((size_t)which * 8 + b) * 8 + by) * NP + n0 + t] = s;
    }
}

// ---------------- Kernel A2: reduce norm partials ----------------
__global__ __launch_bounds__(256)
void norms_reduce_kernel(const float* __restrict__ partial,
                         float* __restrict__ norm1, float* __restrict__ norm2) {
    int id = blockIdx.x * 256 + threadIdx.x;   // over 2*B*N
    if (id >= 2 * B * N) return;
    int which = id / (B * N);
    int r = id % (B * N);
    int b = r / N, n = r % N;
    float s = 0.f;
    #pragma unroll
    for (int dt = 0; dt < 8; ++dt)
        s += partial[(((size_t)which * 8 + b) * 8 + dt) * NP + n];
    (which ? norm2 : norm1)[b * N + n] = sqrtf(s);
}

// ---------------- Kernel B (fallback path): column norms ----------------
__global__ __launch_bounds__(256)
void norms_kernel(const float* __restrict__ fs1, const float* __restrict__ fs2,
                  float* __restrict__ norm1, float* __restrict__ norm2) {
    int bid   = blockIdx.x;
    int ntile = bid % 25;
    int b     = (bid / 25) % B;
    int which = bid / (25 * B);
    const float* src = which ? fs2 : fs1;
    float*       dst = which ? norm2 : norm1;

    int t = threadIdx.x, nl = t & 63, doff = t >> 6;
    int n = ntile * 64 + nl;
    const float* base = src + (size_t)b * D * N + n;
    float acc = 0.f;
    for (int d = doff; d < D; d += 4) {
        float v = base[(size_t)d * N];
        acc = fmaf(v, v, acc);
    }
    __shared__ float red[4][64];
    red[doff][nl] = acc;
    __syncthreads();
    if (t < 64) {
        float s = red[0][t] + red[1][t] + red[2][t] + red[3][t];
        dst[b * N + ntile * 64 + t] = sqrtf(s);
    }
}

// ---------------- Kernel C: bf16x3 MFMA GEMM, pipelined 128x256 ----------------
__device__ __forceinline__ s8 ldfrag(const short* tile, int row, int l) {
    int s = ((l >> 4) ^ (row >> 1)) & 3;   // bank-spread XOR swizzle
    return *(const s8*)(tile + row * 32 + s * 8);
}

__global__ __launch_bounds__(512, 2)
void gemm_mfma_kernel(const short* __restrict__ Yh, const short* __restrict__ Ym, const short* __restrict__ Yl,
                      const short* __restrict__ Xh, const short* __restrict__ Xm, const short* __restrict__ Xl,
                      const float* __restrict__ norm1, const float* __restrict__ norm2,
                      unsigned int* __restrict__ mx, float* __restrict__ out) {
    // LDS: 2 buffers x [A(Y): 3 x 128x32 | B(X): 3 x 256x32] bf16 = 2 x 72KB
    __shared__ short lds[2][36864];

    int lin = blockIdx.x;          // 728 = 8 XCD * 91
    int b    = lin & 7;            // one batch per XCD (T1)
    int rem  = lin >> 3;           // 0..90
    int mblk = rem % 13;           // m fastest -> B-tile L2 reuse
    int nblk = rem / 13;           // 0..6
    int m0 = mblk * 128, n0 = nblk * 256;

    int t = threadIdx.x, l = t & 63, w = t >> 6;
    int mwoff = (w >> 2) * 64;     // wave tile 64x64
    int nwoff = (w & 3) * 64;
    size_t bNP = (size_t)b * NP;

    // --- per-wave staging plan: 9 global_load_lds per K-step ---
    const short* Ab[3] = {Yh, Ym, Yl};
    const short* Bb[3] = {Xh, Xm, Xl};
    const short* gp[9];
    int lo[9];
    #pragma unroll
    for (int j = 0; j < 9; ++j) {
        int q = w * 9 + j;
        int s, rg, rows0, tbase;
        const short* base;
        if (q < 24) { s = q >> 3;            rg = q & 7;  base = Ab[s]; tbase = s * 4096;         rows0 = m0; }
        else        { int q2 = q - 24; s = q2 >> 4; rg = q2 & 15; base = Bb[s]; tbase = 12288 + s * 8192; rows0 = n0; }
        int rowl = rg * 16 + (l >> 2);
        int slot = ((l & 3) ^ (rowl >> 1)) & 3;
        int grow = rows0 + rowl;
        if (grow > NP - 1) grow = NP - 1;     // clamp partial n-block reads in-bounds
        gp[j] = base + (bNP + grow) * (size_t)D + slot * 8;
        lo[j] = tbase + rg * 512;
    }

    #define STAGE(nb)                                              \
    {   _Pragma("unroll")                                          \
        for (int j = 0; j < 9; ++j) {                              \
            gload16(gp[j], &lds[nb][lo[j]]);                       \
            gp[j] += 32;                                           \
        }                                                          \
    }

    f32x4 acc[4][4];
    #pragma unroll
    for (int i = 0; i < 4; i++)
        #pragma unroll
        for (int j = 0; j < 4; j++) acc[i][j] = (f32x4)0.f;

    STAGE(0);   // prologue: K-step 0 into buf 0

    constexpr int ap[6] = {0, 0, 1, 1, 0, 2};
    constexpr int bp[6] = {0, 1, 0, 1, 2, 0};

    for (int tt = 0; tt < 16; ++tt) {
        int cur = tt & 1;
        if (tt < 15) {
            STAGE(cur ^ 1);                                        // prefetch next K-step
            asm volatile("s_waitcnt vmcnt(9)" ::: "memory");       // cur buf's 9 done; 9 stay in flight
        } else {
            asm volatile("s_waitcnt vmcnt(0)" ::: "memory");
        }
        __builtin_amdgcn_s_barrier();
        asm volatile("" ::: "memory");

        const short* At = &lds[cur][0];
        const short* Bt = &lds[cur][12288];

        s8 bf[3][4];
        #pragma unroll
        for (int nj = 0; nj < 4; ++nj) {
            int nrow = nwoff + nj * 16 + (l & 15);
            #pragma unroll
            for (int s = 0; s < 3; ++s)
                bf[s][nj] = ldfrag(Bt + s * 8192, nrow, l);
        }
        __builtin_amdgcn_s_setprio(1);
        #pragma unroll
        for (int mp = 0; mp < 2; ++mp) {
            s8 af[3][2];
            #pragma unroll
            for (int ii = 0; ii < 2; ++ii) {
                int mrow = mwoff + (mp * 2 + ii) * 16 + (l & 15);
                #pragma unroll
                for (int s = 0; s < 3; ++s)
                    af[s][ii] = ldfrag(At + s * 4096, mrow, l);
            }
            #pragma unroll
            for (int p = 0; p < 6; ++p)
                #pragma unroll
                for (int ii = 0; ii < 2; ++ii)
                    #pragma unroll
                    for (int nj = 0; nj < 4; ++nj)
                        acc[mp * 2 + ii][nj] = __builtin_amdgcn_mfma_f32_16x16x32_bf16(
                            af[ap[p]][ii], bf[bp[p]][nj], acc[mp * 2 + ii][nj], 0, 0, 0);
        }
        __builtin_amdgcn_s_setprio(0);
        asm volatile("s_waitcnt lgkmcnt(0)" ::: "memory");         // LDS reads retired before reuse
        __builtin_amdgcn_s_barrier();
    }
    #undef STAGE

    // epilogue: cos -> K = exp((c-1)*10); store out[b][m][n]; per-n max
    int hi4 = l >> 4;
    float n1v[4];
    int   ng[4];
    #pragma unroll
    for (int nj = 0; nj < 4; ++nj) {
        ng[nj]  = n0 + nwoff + nj * 16 + (l & 15);
        n1v[nj] = (ng[nj] < N) ? norm1[b * N + ng[nj]] : 1.f;
    }
    float pmax[4] = {0.f, 0.f, 0.f, 0.f};
    size_t obase = (size_t)b * N * N;

    #pragma unroll
    for (int mi = 0; mi < 4; ++mi) {
        #pragma unroll
        for (int r = 0; r < 4; ++r) {
            int mg = m0 + mwoff + mi * 16 + hi4 * 4 + r;
            bool mok = (mg < N);
            float n2v = mok ? norm2[b * N + mg] : 1.f;
            #pragma unroll
            for (int nj = 0; nj < 4; ++nj) {
                float c = acc[mi][nj][r] / (n2v * n1v[nj] + EPS_K);
                float k = expf((c - 1.f) * INV_T);
                if (!mok) k = 0.f;
                pmax[nj] = fmaxf(pmax[nj], k);
                if (mok && ng[nj] < N)
                    out[obase + (size_t)mg * N + ng[nj]] = k;
            }
        }
    }
    #pragma unroll
    for (int nj = 0; nj < 4; ++nj) {
        float v = pmax[nj];
        v = fmaxf(v, __shfl_xor(v, 16, 64));
        v = fmaxf(v, __shfl_xor(v, 32, 64));
        if (hi4 == 0 && ng[nj] < N)
            atomicMax(&mx[b * N + ng[nj]], __float_as_uint(v));
    }
}

// ---------------- fp32 fallback GEMM (used if ws too small) ----------------
#define BK 16
#define BT 128
__global__ __launch_bounds__(256)
void gemm_exp_kernel(const float* __restrict__ fs1, const float* __restrict__ fs2,
                     const float* __restrict__ norm1, const float* __restrict__ norm2,
                     unsigned int* __restrict__ mx, float* __restrict__ out) {
    int m0 = blockIdx.x * BT, n0 = blockIdx.y * BT, b = blockIdx.z;
    int t = threadIdx.x, tx = t & 15, ty = t >> 4;
    __shared__ float Xs[BK][BT];
    __shared__ float Ys[BK][BT];
    __shared__ float red[BT][17];
    const float* Xb = fs1 + (size_t)b * D * N;
    const float* Yb = fs2 + (size_t)b * D * N;
    float acc[8][8];
    #pragma unroll
    for (int i = 0; i < 8; i++)
        #pragma unroll
        for (int j = 0; j < 8; j++) acc[i][j] = 0.f;
    int r0 = t >> 5, c4 = (t & 31) * 4;
    bool xok = (n0 + c4) < N, yok = (m0 + c4) < N;
    for (int kk = 0; kk < D; kk += BK) {
        #pragma unroll
        for (int rr = 0; rr < 2; rr++) {
            int r = r0 + rr * 8, d = kk + r;
            float4 xv = make_float4(0, 0, 0, 0), yv = make_float4(0, 0, 0, 0);
            if (xok) xv = *(const float4*)&Xb[(size_t)d * N + n0 + c4];
            if (yok) yv = *(const float4*)&Yb[(size_t)d * N + m0 + c4];
            *(float4*)&Xs[r][c4] = xv;
            *(float4*)&Ys[r][c4] = yv;
        }
        __syncthreads();
        #pragma unroll
        for (int d = 0; d < BK; d++) {
            float4 a0 = *(const float4*)&Xs[d][ty * 4];
            float4 a1 = *(const float4*)&Xs[d][64 + ty * 4];
            float4 b0 = *(const float4*)&Ys[d][tx * 4];
            float4 b1 = *(const float4*)&Ys[d][64 + tx * 4];
            float av[8] = {a0.x, a0.y, a0.z, a0.w, a1.x, a1.y, a1.z, a1.w};
            float bv[8] = {b0.x, b0.y, b0.z, b0.w, b1.x, b1.y, b1.z, b1.w};
            #pragma unroll
            for (int i = 0; i < 8; i++)
                #pragma unroll
                for (int j = 0; j < 8; j++)
                    acc[i][j] = fmaf(av[i], bv[j], acc[i][j]);
        }
        __syncthreads();
    }
    int ng[8], mg[8];
    float n1v[8], n2v[8];
    #pragma unroll
    for (int q = 0; q < 8; q++) {
        ng[q] = n0 + ((q < 4) ? (ty * 4 + q) : (64 + ty * 4 + q - 4));
        mg[q] = m0 + ((q < 4) ? (tx * 4 + q) : (64 + tx * 4 + q - 4));
        n1v[q] = (ng[q] < N) ? norm1[b * N + ng[q]] : 1.f;
        n2v[q] = (mg[q] < N) ? norm2[b * N + mg[q]] : 1.f;
    }
    float pmax[8];
    #pragma unroll
    for (int i = 0; i < 8; i++) pmax[i] = 0.f;
    size_t obase = (size_t)b * N * N;
    #pragma unroll
    for (int j = 0; j < 8; j++) {
        float kcol[8];
        #pragma unroll
        for (int i = 0; i < 8; i++) {
            float c = acc[i][j] / (n1v[i] * n2v[j] + EPS_K);
            float k = expf((c - 1.f) * INV_T);
            if (mg[j] >= N) k = 0.f;
            kcol[i] = k;
            pmax[i] = fmaxf(pmax[i], k);
        }
        if (mg[j] < N) {
            size_t rowb = obase + (size_t)mg[j] * N;
            float4 v0 = {kcol[0], kcol[1], kcol[2], kcol[3]};
            *(float4*)&out[rowb + ng[0]] = v0;
            if (ng[4] < N) {
                float4 v1 = {kcol[4], kcol[5], kcol[6], kcol[7]};
                *(float4*)&out[rowb + ng[4]] = v1;
            }
        }
    }
    #pragma unroll
    for (int q = 0; q < 8; q++) {
        int nloc = (q < 4) ? (ty * 4 + q) : (64 + ty * 4 + q - 4);
        red[nloc][tx] = pmax[q];
    }
    __syncthreads();
    if (t < BT) {
        float mval = red[t][0];
        #pragma unroll
        for (int x = 1; x < 16; x++) mval = fmaxf(mval, red[t][x]);
        int n = n0 + t;
        if (n < N) atomicMax(&mx[b * N + n], __float_as_uint(mval));
    }
}

// ---------------- Kernel D: in-place fixup + argmax (float4) ----------------
__global__ __launch_bounds__(256)
void fix_argmax_kernel(float* __restrict__ out, const unsigned int* __restrict__ mx,
                       int* __restrict__ bestm) {
    int nt = blockIdx.x;      // 0..6 (n chunks of 256)
    int mq = blockIdx.y;      // 0..3 (m quarters of 400)
    int b  = blockIdx.z;
    int t  = threadIdx.x;
    int n0 = nt * 256 + (t & 63) * 4;
    int moff = t >> 6;
    bool ok = (n0 < N);       // N%4==0 -> full float4 valid or fully out

    int b0 = 0x7fffffff, b1 = 0x7fffffff, b2 = 0x7fffffff, b3 = 0x7fffffff;
    float4 mxv = make_float4(0, 0, 0, 0);
    if (ok) {
        mxv = *(const float4*)&((const float*)mx)[b * N + n0];
        size_t base = (size_t)b * N * N + n0;
        int mend = mq * 400 + 400;
        for (int m = mq * 400 + moff; m < mend; m += 4) {
            size_t idx = base + (size_t)m * N;
            float4 v = *(float4*)&out[idx];
            float4 o;
            o.x = (v.x - mxv.x) * SCALE_K;
            o.y = (v.y - mxv.y) * SCALE_K;
            o.z = (v.z - mxv.z) * SCALE_K;
            o.w = (v.w - mxv.w) * SCALE_K;
            *(float4*)&out[idx] = o;
            if (v.x == mxv.x) b0 = min(b0, m);
            if (v.y == mxv.y) b1 = min(b1, m);
            if (v.z == mxv.z) b2 = min(b2, m);
            if (v.w == mxv.w) b3 = min(b3, m);
        }
    }
    __shared__ int red[4][64][4];
    red[moff][t & 63][0] = b0;
    red[moff][t & 63][1] = b1;
    red[moff][t & 63][2] = b2;
    red[moff][t & 63][3] = b3;
    __syncthreads();
    if (moff == 0 && ok) {
        #pragma unroll
        for (int j = 0; j < 4; ++j) {
            int bm = min(min(red[0][t & 63][j], red[1][t & 63][j]),
                         min(red[2][t & 63][j], red[3][t & 63][j]));
            if (bm < 0x7fffffff) atomicMin(&bestm[b * N + n0 + j], bm);
        }
    }
}

// ---------------- Kernel E: flow + certainty ----------------
__global__ __launch_bounds__(256)
void flow_kernel(float* __restrict__ out, const int* __restrict__ bestm) {
    int id = blockIdx.x * 256 + threadIdx.x;
    if (id >= B * N) return;
    int b = id / N, n = id % N;
    int bm = bestm[id];
    int i = bm / NRES, j = bm % NRES;
    const float step = 1.95f / 39.f;
    float gx = fmaf(step, (float)j, -0.975f);
    float gy = fmaf(step, (float)i, -0.975f);
    const size_t CERT_OFF = (size_t)B * N * N;
    const size_t FLOW_OFF = CERT_OFF + (size_t)B * N;
    out[CERT_OFF + id] = 0.f;
    out[FLOW_OFF + (size_t)(b * 2) * N + n]     = gx;
    out[FLOW_OFF + (size_t)(b * 2 + 1) * N + n] = gy;
}

extern "C" void kernel_launch(void* const* d_in, const int* in_sizes, int n_in,
                              void* d_out, int out_size, void* d_ws, size_t ws_size,
                              hipStream_t stream) {
    const float* fs1 = (const float*)d_in[0];
    const float* fs2 = (const float*)d_in[1];
    float* out = (float*)d_out;

    const size_t SPLIT = (size_t)B * NP * D;                 // elems per split
    const size_t NEED  = 6 * SPLIT * sizeof(short) + 4 * (size_t)B * N * 4 + 64;

    if (ws_size >= NEED) {
        short* Yh = (short*)d_ws;
        short* Ym = Yh + SPLIT;
        short* Yl = Ym + SPLIT;
        short* Xh = Yl + SPLIT;
        short* Xm = Xh + SPLIT;
        short* Xl = Xm + SPLIT;
        float* norm1 = (float*)(Xl + SPLIT);
        float* norm2 = norm1 + B * N;
        unsigned int* mx = (unsigned int*)(norm2 + B * N);
        int* bestm = (int*)(mx + B * N);
        float* partial = out;    // 852KB scratch inside gm_cls, overwritten by gemm

        hipMemsetAsync(mx, 0, B * N * sizeof(unsigned int), stream);
        hipMemsetAsync(bestm, 0x7f, B * N * sizeof(int), stream);

        split_transpose_kernel<<<dim3(26, 8, 16), 256, 0, stream>>>(
            fs1, fs2, Xh, Xm, Xl, Yh, Ym, Yl, partial);
        norms_reduce_kernel<<<dim3(100), 256, 0, stream>>>(partial, norm1, norm2);
        gemm_mfma_kernel<<<dim3(728), 512, 0, stream>>>(Yh, Ym, Yl, Xh, Xm, Xl,
                                                        norm1, norm2, mx, out);
        fix_argmax_kernel<<<dim3(7, 4, B), 256, 0, stream>>>(out, mx, bestm);
        flow_kernel<<<dim3((B * N + 255) / 256), 256, 0, stream>>>(out, bestm);
    } else {
        float* norm1 = (float*)d_ws;
        float* norm2 = norm1 + B * N;
        unsigned int* mx = (unsigned int*)(norm2 + B * N);
        int* bestm = (int*)(mx + B * N);

        hipMemsetAsync(mx, 0, B * N * sizeof(unsigned int), stream);
        hipMemsetAsync(bestm, 0x7f, B * N * sizeof(int), stream);

        norms_kernel<<<dim3(2 * B * 25), 256, 0, stream>>>(fs1, fs2, norm1, norm2);
        gemm_exp_kernel<<<dim3(13, 13, B), 256, 0, stream>>>(fs1, fs2, norm1, norm2, mx, out);
        fix_argmax_kernel<<<dim3(7, 4, B), 256, 0, stream>>>(out, mx, bestm);
        flow_kernel<<<dim3((B * N + 255) / 256), 256, 0, stream>>>(out, bestm);
    }
}